// Round 1
// baseline (212.937 us; speedup 1.0000x reference)
//
#include <hip/hip_runtime.h>
#include <hip/hip_bf16.h>
#include <math.h>

// EulerCausalAttention on MI355X (gfx950).
// Pipeline: prep (Q/K euler features, x->bf16) ; wconv (weights->bf16) ;
//           V = x @ v_w^T  (transposed-output GEMM -> Vt[b,h,d,s]) ;
//           causal flash attention (bf16 MFMA 16x16x32) ;
//           out = attn_out @ out_w^T (f32 output).
// All matmuls: bf16 inputs, f32 MFMA accumulate. absmax threshold 6.8e-2 >> bf16 error (~1e-2).

typedef __attribute__((ext_vector_type(8))) __bf16 bf16x8;
typedef __attribute__((ext_vector_type(4))) float f32x4;
typedef unsigned short ushort_t;
typedef unsigned int uint_t;

#define LUTC 651.8986469044033f      // 4096 / (2*pi)
#define ANG 0.0015339807878856412f   // 2*pi / 4096
#define INVSCALE 0.08838834764831845f // 1/sqrt(128)

__device__ __forceinline__ ushort_t f2bf(float f) {
  union { __bf16 b; ushort_t u; } cv;
  cv.b = (__bf16)f;
  return cv.u;
}

__device__ __forceinline__ void store8(ushort_t* p, const ushort_t v[8]) {
  uint4 u;
  u.x = (uint_t)v[0] | ((uint_t)v[1] << 16);
  u.y = (uint_t)v[2] | ((uint_t)v[3] << 16);
  u.z = (uint_t)v[4] | ((uint_t)v[5] << 16);
  u.w = (uint_t)v[6] | ((uint_t)v[7] << 16);
  *(uint4*)p = u;
}

// async global->LDS, 16B per lane. LDS dest is wave-uniform base + lane*16.
__device__ __forceinline__ void gl_lds16(const void* g, void* l) {
  __builtin_amdgcn_global_load_lds(
      (__attribute__((address_space(1))) void*)(g),
      (__attribute__((address_space(3))) void*)(l),
      16, 0, 0);
}

// ---------------------------------------------------------------- prep ------
// Q[b,h,s,0:64]=cos/SCALE, Q[...,64:128]=sin/SCALE ; K same unscaled ; xb = bf16(x).
__global__ __launch_bounds__(256) void prep_kernel(
    const float* __restrict__ x, const float* __restrict__ wq, const float* __restrict__ bq,
    const float* __restrict__ wk, const float* __restrict__ bk,
    ushort_t* __restrict__ Qs, ushort_t* __restrict__ Ks, ushort_t* __restrict__ xb)
{
  int t = blockIdx.x * 256 + threadIdx.x;   // 131072 threads
  int dm8 = t & 127;
  int g = t >> 7;                            // token group of 4
  int dm0 = dm8 * 8;
  int h = dm0 >> 6, d0 = dm0 & 63;

  float aq[8], cq[8], ak[8], ck[8];
#pragma unroll
  for (int j = 0; j < 8; ++j) {
    aq[j] = LUTC / (1.0f + fabsf(wq[dm0 + j]));
    cq[j] = LUTC * bq[dm0 + j];
    ak[j] = LUTC / (1.0f + fabsf(wk[dm0 + j]));
    ck[j] = LUTC * bk[dm0 + j];
  }
  for (int i = 0; i < 4; ++i) {
    int bs = g * 4 + i;
    int b = bs >> 11, s = bs & 2047;
    const float4* xp4 = (const float4*)(x + (size_t)bs * 1024 + dm0);
    float4 xa = xp4[0], xbv4 = xp4[1];
    float xv[8] = {xa.x, xa.y, xa.z, xa.w, xbv4.x, xbv4.y, xbv4.z, xbv4.w};
    ushort_t qc[8], qs[8], kc[8], ks[8], xo[8];
#pragma unroll
    for (int j = 0; j < 8; ++j) {
      int iq = ((int)rintf(fmaf(xv[j], aq[j], cq[j]))) & 4095;
      float sq, cqv;
      __sincosf((float)iq * ANG, &sq, &cqv);
      int ik = ((int)rintf(fmaf(xv[j], ak[j], ck[j]))) & 4095;
      float sk, ckv;
      __sincosf((float)ik * ANG, &sk, &ckv);
      qc[j] = f2bf(cqv * INVSCALE);
      qs[j] = f2bf(sq * INVSCALE);
      kc[j] = f2bf(ckv);
      ks[j] = f2bf(sk);
      xo[j] = f2bf(xv[j]);
    }
    size_t qb = ((size_t)(b * 16 + h) * 2048 + s) * 128 + d0;
    store8(Qs + qb, qc);        store8(Qs + qb + 64, qs);
    store8(Ks + qb, kc);        store8(Ks + qb + 64, ks);
    store8(xb + (size_t)bs * 1024 + dm0, xo);
  }
}

// ---------------------------------------------------------------- wconv -----
__global__ __launch_bounds__(256) void wconv_kernel(
    const float* __restrict__ vw, const float* __restrict__ ow,
    ushort_t* __restrict__ vwb, ushort_t* __restrict__ owb)
{
  int t = blockIdx.x * 256 + threadIdx.x;   // 262144 threads
  const float* src;
  ushort_t* dst;
  int i;
  if (t < 131072) { src = vw; dst = vwb; i = t; }
  else            { src = ow; dst = owb; i = t - 131072; }
  const float4* p4 = (const float4*)(src + (size_t)i * 8);
  float4 a = p4[0], b = p4[1];
  float v[8] = {a.x, a.y, a.z, a.w, b.x, b.y, b.z, b.w};
  ushort_t o[8];
#pragma unroll
  for (int j = 0; j < 8; ++j) o[j] = f2bf(v[j]);
  store8(dst + (size_t)i * 8, o);
}

// ---------------------------------------------------------------- GEMM ------
// C[m][n] = sum_e A[m][e] * B[n][e]   (both row-major along e, bf16)
// EPI 0: f32 store C[m*N+n].   EPI 1: bf16 store to Vt layout (m=dmodel, n=token).
template <int EPI>
__global__ __launch_bounds__(256) void gemm_nt(
    const ushort_t* __restrict__ A, const ushort_t* __restrict__ B,
    float* __restrict__ Cf, ushort_t* __restrict__ Cb, int M, int N, int K)
{
  __shared__ __align__(16) ushort_t As[128 * 64];
  __shared__ __align__(16) ushort_t Bs[128 * 64];
  const int l = threadIdx.x & 63;
  const int w = threadIdx.x >> 6;
  const int wm = w >> 1, wn = w & 1;
  const int mt = blockIdx.x % (M >> 7);
  const int nt = blockIdx.x / (M >> 7);
  const int m0 = mt << 7, n0 = nt << 7;

  const f32x4 zero4 = {0.f, 0.f, 0.f, 0.f};
  f32x4 acc[4][4];
#pragma unroll
  for (int i = 0; i < 4; ++i)
#pragma unroll
    for (int j = 0; j < 4; ++j) acc[i][j] = zero4;

  for (int k0 = 0; k0 < K; k0 += 64) {
#pragma unroll
    for (int i = 0; i < 4; ++i) {
      int ci = (w * 4 + i) * 64 + l;
      int r = ci >> 3, c = (ci & 7) ^ (r & 7);           // pre-swizzled source
      gl_lds16(A + (size_t)(m0 + r) * K + k0 + c * 8, &As[(w * 4 + i) * 512]);
      gl_lds16(B + (size_t)(n0 + r) * K + k0 + c * 8, &Bs[(w * 4 + i) * 512]);
    }
    __syncthreads();
#pragma unroll
    for (int kk = 0; kk < 2; ++kk) {
      bf16x8 af[4], bfr[4];
#pragma unroll
      for (int mi = 0; mi < 4; ++mi) {
        int r = wm * 64 + mi * 16 + (l & 15);
        int ch = ((l >> 4) + 4 * kk) ^ (r & 7);
        af[mi] = *(const bf16x8*)&As[r * 64 + ch * 8];
      }
#pragma unroll
      for (int ni = 0; ni < 4; ++ni) {
        int r = wn * 64 + ni * 16 + (l & 15);
        int ch = ((l >> 4) + 4 * kk) ^ (r & 7);
        bfr[ni] = *(const bf16x8*)&Bs[r * 64 + ch * 8];
      }
#pragma unroll
      for (int mi = 0; mi < 4; ++mi)
#pragma unroll
        for (int ni = 0; ni < 4; ++ni)
          acc[mi][ni] = __builtin_amdgcn_mfma_f32_16x16x32_bf16(af[mi], bfr[ni], acc[mi][ni], 0, 0, 0);
    }
    __syncthreads();
  }

#pragma unroll
  for (int mi = 0; mi < 4; ++mi)
#pragma unroll
    for (int ni = 0; ni < 4; ++ni)
#pragma unroll
      for (int reg = 0; reg < 4; ++reg) {
        int row = m0 + wm * 64 + mi * 16 + (l >> 4) * 4 + reg;
        int col = n0 + wn * 64 + ni * 16 + (l & 15);
        float v = acc[mi][ni][reg];
        if (EPI == 0) {
          Cf[(size_t)row * N + col] = v;
        } else {
          size_t o = (size_t)(col >> 11) * (1024 * 2048) + (size_t)row * 2048 + (col & 2047);
          Cb[o] = f2bf(v);
        }
      }
}

// ------------------------------------------------------------- attention ----
// Per block: one (b,h) and one 64-row q-block. 4 waves x 16 q-rows.
// Q[b,h,s,128] (1/SCALE folded), K[b,h,s,128], Vt[b,h,d=64,s], out Ob[b,s,h*64+d] bf16.
__global__ __launch_bounds__(256) void attn_kernel(
    const ushort_t* __restrict__ Qs, const ushort_t* __restrict__ Ks,
    const ushort_t* __restrict__ Vt, ushort_t* __restrict__ Ob)
{
  const int S = 2048;
  const int qt = blockIdx.x & 31;
  const int bh = blockIdx.x >> 5;
  const int l = threadIdx.x & 63;
  const int w = threadIdx.x >> 6;

  __shared__ __align__(16) ushort_t Kl[64 * 128];   // swizzled, 16KB
  __shared__ __align__(16) ushort_t Vl[64 * 64];    // [d][k] swizzled, 8KB
  __shared__ __align__(16) ushort_t Pl[4][16 * 64]; // per-wave P, swizzled, 8KB

  const int q0 = qt * 64 + w * 16;
  bf16x8 qf[4];
  {
    const ushort_t* qp = Qs + ((size_t)bh * S + q0 + (l & 15)) * 128 + (l >> 4) * 8;
#pragma unroll
    for (int e = 0; e < 4; ++e) qf[e] = *(const bf16x8*)(qp + e * 32);
  }

  const f32x4 zero4 = {0.f, 0.f, 0.f, 0.f};
  float mreg[4], lreg[4];
  f32x4 accO[4];
#pragma unroll
  for (int r = 0; r < 4; ++r) { mreg[r] = -__builtin_inff(); lreg[r] = 0.f; accO[r] = zero4; }

  for (int kt = 0; kt <= qt; ++kt) {
    const int kb = kt * 64;
#pragma unroll
    for (int i = 0; i < 4; ++i) {                   // K tile 64x128
      int ci = (w * 4 + i) * 64 + l;
      int r = ci >> 4, c = (ci & 15) ^ (r & 7);
      gl_lds16(Ks + ((size_t)bh * S + kb + r) * 128 + c * 8, &Kl[(w * 4 + i) * 512]);
    }
#pragma unroll
    for (int i = 0; i < 2; ++i) {                   // V tile 64(d) x 64(k)
      int ci = (w * 2 + i) * 64 + l;
      int r = ci >> 3, c = (ci & 7) ^ (r & 7);
      gl_lds16(Vt + ((size_t)bh * 64 + r) * S + kb + c * 8, &Vl[(w * 2 + i) * 512]);
    }
    __syncthreads();

    // S = Q K^T (1/SCALE pre-folded into Q)
    f32x4 sc[4];
#pragma unroll
    for (int ns = 0; ns < 4; ++ns) sc[ns] = zero4;
#pragma unroll
    for (int e = 0; e < 4; ++e)
#pragma unroll
      for (int ns = 0; ns < 4; ++ns) {
        int r = ns * 16 + (l & 15);
        int ch = ((l >> 4) + 4 * e) ^ (r & 7);
        bf16x8 kf = *(const bf16x8*)&Kl[r * 128 + ch * 8];
        sc[ns] = __builtin_amdgcn_mfma_f32_16x16x32_bf16(qf[e], kf, sc[ns], 0, 0, 0);
      }

    // online softmax (D layout: row=(l>>4)*4+reg, col=l&15+16*ns)
    float rmx[4];
#pragma unroll
    for (int r = 0; r < 4; ++r) rmx[r] = -__builtin_inff();
#pragma unroll
    for (int ns = 0; ns < 4; ++ns) {
      int kg = kb + ns * 16 + (l & 15);
#pragma unroll
      for (int reg = 0; reg < 4; ++reg) {
        int qg = q0 + (l >> 4) * 4 + reg;
        float v = (kg <= qg) ? sc[ns][reg] : -__builtin_inff();
        rmx[reg] = fmaxf(rmx[reg], v);
      }
    }
#pragma unroll
    for (int reg = 0; reg < 4; ++reg) {
#pragma unroll
      for (int off = 1; off < 16; off <<= 1)
        rmx[reg] = fmaxf(rmx[reg], __shfl_xor(rmx[reg], off));
      float mn = fmaxf(mreg[reg], rmx[reg]);
      float f = __expf(mreg[reg] - mn);
      mreg[reg] = mn;
      lreg[reg] *= f;
#pragma unroll
      for (int nd = 0; nd < 4; ++nd) accO[nd][reg] *= f;
    }
    float rs[4] = {0.f, 0.f, 0.f, 0.f};
#pragma unroll
    for (int ns = 0; ns < 4; ++ns) {
      int kg = kb + ns * 16 + (l & 15);
#pragma unroll
      for (int reg = 0; reg < 4; ++reg) {
        int qg = q0 + (l >> 4) * 4 + reg;
        float p = (kg <= qg) ? __expf(sc[ns][reg] - mreg[reg]) : 0.f;
        rs[reg] += p;
        int row = (l >> 4) * 4 + reg;
        int col = ns * 16 + (l & 15);
        int ch = (col >> 3) ^ (row & 7);
        Pl[w][row * 64 + ch * 8 + (col & 7)] = f2bf(p);
      }
    }
#pragma unroll
    for (int reg = 0; reg < 4; ++reg) {
#pragma unroll
      for (int off = 1; off < 16; off <<= 1)
        rs[reg] += __shfl_xor(rs[reg], off);
      lreg[reg] += rs[reg];
    }
    __syncthreads();   // P visible before PV reads

    // O += P V
#pragma unroll
    for (int kk = 0; kk < 2; ++kk) {
      int prow = l & 15;
      int pch = ((l >> 4) + 4 * kk) ^ (prow & 7);
      bf16x8 pf = *(const bf16x8*)&Pl[w][prow * 64 + pch * 8];
#pragma unroll
      for (int nd = 0; nd < 4; ++nd) {
        int vr = nd * 16 + (l & 15);
        int vch = ((l >> 4) + 4 * kk) ^ (vr & 7);
        bf16x8 vf = *(const bf16x8*)&Vl[vr * 64 + vch * 8];
        accO[nd] = __builtin_amdgcn_mfma_f32_16x16x32_bf16(pf, vf, accO[nd], 0, 0, 0);
      }
    }
    __syncthreads();   // LDS free for next k-tile
  }

  const int b = bh >> 4, h = bh & 15;
  float inv[4];
#pragma unroll
  for (int reg = 0; reg < 4; ++reg) inv[reg] = 1.0f / lreg[reg];
#pragma unroll
  for (int nd = 0; nd < 4; ++nd)
#pragma unroll
    for (int reg = 0; reg < 4; ++reg) {
      int qg = q0 + (l >> 4) * 4 + reg;
      size_t o = ((size_t)(b * 2048 + qg)) * 1024 + h * 64 + nd * 16 + (l & 15);
      Ob[o] = f2bf(accO[nd][reg] * inv[reg]);
    }
}

// ---------------------------------------------------------------- launch ----
extern "C" void kernel_launch(void* const* d_in, const int* in_sizes, int n_in,
                              void* d_out, int out_size, void* d_ws, size_t ws_size,
                              hipStream_t stream) {
  const float* x  = (const float*)d_in[0];
  const float* wq = (const float*)d_in[1];
  const float* bq = (const float*)d_in[2];
  const float* wk = (const float*)d_in[3];
  const float* bk = (const float*)d_in[4];
  const float* vw = (const float*)d_in[5];
  const float* ow = (const float*)d_in[6];
  float* out = (float*)d_out;

  char* ws = (char*)d_ws;
  ushort_t* Qs  = (ushort_t*)(ws);                      // 16 MB  [32][2048][128]
  ushort_t* Ksb = (ushort_t*)(ws + (16u << 20));        // 16 MB  [32][2048][128]
  ushort_t* Vtb = (ushort_t*)(ws + (32u << 20));        //  8 MB  [32][64][2048]
  ushort_t* xbb = (ushort_t*)(ws + (40u << 20));        //  8 MB  [4096][1024]
  ushort_t* Obb = (ushort_t*)(ws + (48u << 20));        //  8 MB  [4096][1024]
  ushort_t* vwb = (ushort_t*)(ws + (56u << 20));        //  2 MB
  ushort_t* owb = (ushort_t*)(ws + (58u << 20));        //  2 MB

  prep_kernel<<<512, 256, 0, stream>>>(x, wq, bq, wk, bk, Qs, Ksb, xbb);
  wconv_kernel<<<1024, 256, 0, stream>>>(vw, ow, vwb, owb);
  // Vt[dm][token]: M=1024 rows of v_w, N=4096 tokens
  gemm_nt<1><<<256, 256, 0, stream>>>(vwb, xbb, nullptr, Vtb, 1024, 4096, 1024);
  attn_kernel<<<1024, 256, 0, stream>>>(Qs, Ksb, Vtb, Obb);
  // out[token][dm] f32: M=4096 tokens, N=1024
  gemm_nt<0><<<256, 256, 0, stream>>>(Obb, owb, out, nullptr, 4096, 1024, 1024);
}

// Round 2
// 119.569 us; speedup vs baseline: 1.7809x; 1.7809x over previous
//
#include <hip/hip_runtime.h>
#include <hip/hip_bf16.h>
#include <math.h>

// EulerCausalAttention on MI355X (gfx950).
// Pipeline: prep (Q/K euler features, x->bf16) ; wconv (weights->bf16) ;
//           V = x @ v_w^T  (transposed-output GEMM -> Vt[b,h,d,s]) ;
//           causal flash attention (bf16 MFMA 16x16x32, swapped-QK, reg-P) ;
//           out = attn_out @ out_w^T (f32 output).
// Attention uses a FIXED softmax offset (scores provably bounded: |s| <= 128/sqrt(128)
// = 11.31 < 12), so no online max tracking, no rescale, denominator reduced once at end.

typedef __attribute__((ext_vector_type(8))) __bf16 bf16x8;
typedef __attribute__((ext_vector_type(4))) __bf16 bf16x4;
typedef __attribute__((ext_vector_type(4))) float f32x4;
typedef unsigned short ushort_t;
typedef unsigned int uint_t;

#define LUTC 651.8986469044033f      // 4096 / (2*pi)
#define ANG 0.0015339807878856412f   // 2*pi / 4096
#define INVSCALE 0.08838834764831845f // 1/sqrt(128)
#define SOFF 12.0f                    // fixed softmax offset (> max |score| = 11.314)

__device__ __forceinline__ ushort_t f2bf(float f) {
  union { __bf16 b; ushort_t u; } cv;
  cv.b = (__bf16)f;
  return cv.u;
}

__device__ __forceinline__ void store8(ushort_t* p, const ushort_t v[8]) {
  uint4 u;
  u.x = (uint_t)v[0] | ((uint_t)v[1] << 16);
  u.y = (uint_t)v[2] | ((uint_t)v[3] << 16);
  u.z = (uint_t)v[4] | ((uint_t)v[5] << 16);
  u.w = (uint_t)v[6] | ((uint_t)v[7] << 16);
  *(uint4*)p = u;
}

// async global->LDS, 16B per lane. LDS dest is wave-uniform base + lane*16.
__device__ __forceinline__ void gl_lds16(const void* g, void* l) {
  __builtin_amdgcn_global_load_lds(
      (__attribute__((address_space(1))) void*)(g),
      (__attribute__((address_space(3))) void*)(l),
      16, 0, 0);
}

// ---------------------------------------------------------------- prep ------
__global__ __launch_bounds__(256) void prep_kernel(
    const float* __restrict__ x, const float* __restrict__ wq, const float* __restrict__ bq,
    const float* __restrict__ wk, const float* __restrict__ bk,
    ushort_t* __restrict__ Qs, ushort_t* __restrict__ Ks, ushort_t* __restrict__ xb)
{
  int t = blockIdx.x * 256 + threadIdx.x;   // 131072 threads
  int dm8 = t & 127;
  int g = t >> 7;                            // token group of 4
  int dm0 = dm8 * 8;
  int h = dm0 >> 6, d0 = dm0 & 63;
  (void)d0;

  float aq[8], cq[8], ak[8], ck[8];
#pragma unroll
  for (int j = 0; j < 8; ++j) {
    aq[j] = LUTC / (1.0f + fabsf(wq[dm0 + j]));
    cq[j] = LUTC * bq[dm0 + j];
    ak[j] = LUTC / (1.0f + fabsf(wk[dm0 + j]));
    ck[j] = LUTC * bk[dm0 + j];
  }
  for (int i = 0; i < 4; ++i) {
    int bs = g * 4 + i;
    int b = bs >> 11, s = bs & 2047;
    const float4* xp4 = (const float4*)(x + (size_t)bs * 1024 + dm0);
    float4 xa = xp4[0], xbv4 = xp4[1];
    float xv[8] = {xa.x, xa.y, xa.z, xa.w, xbv4.x, xbv4.y, xbv4.z, xbv4.w};
    ushort_t qc[8], qs[8], kc[8], ks[8], xo[8];
#pragma unroll
    for (int j = 0; j < 8; ++j) {
      int iq = ((int)rintf(fmaf(xv[j], aq[j], cq[j]))) & 4095;
      float sq, cqv;
      __sincosf((float)iq * ANG, &sq, &cqv);
      int ik = ((int)rintf(fmaf(xv[j], ak[j], ck[j]))) & 4095;
      float sk, ckv;
      __sincosf((float)ik * ANG, &sk, &ckv);
      qc[j] = f2bf(cqv * INVSCALE);
      qs[j] = f2bf(sq * INVSCALE);
      kc[j] = f2bf(ckv);
      ks[j] = f2bf(sk);
      xo[j] = f2bf(xv[j]);
    }
    size_t qb = ((size_t)(b * 16 + h) * 2048 + s) * 128 + (dm0 & 63);
    store8(Qs + qb, qc);        store8(Qs + qb + 64, qs);
    store8(Ks + qb, kc);        store8(Ks + qb + 64, ks);
    store8(xb + (size_t)bs * 1024 + dm0, xo);
  }
}

// ---------------------------------------------------------------- wconv -----
__global__ __launch_bounds__(256) void wconv_kernel(
    const float* __restrict__ vw, const float* __restrict__ ow,
    ushort_t* __restrict__ vwb, ushort_t* __restrict__ owb)
{
  int t = blockIdx.x * 256 + threadIdx.x;   // 262144 threads
  const float* src;
  ushort_t* dst;
  int i;
  if (t < 131072) { src = vw; dst = vwb; i = t; }
  else            { src = ow; dst = owb; i = t - 131072; }
  const float4* p4 = (const float4*)(src + (size_t)i * 8);
  float4 a = p4[0], b = p4[1];
  float v[8] = {a.x, a.y, a.z, a.w, b.x, b.y, b.z, b.w};
  ushort_t o[8];
#pragma unroll
  for (int j = 0; j < 8; ++j) o[j] = f2bf(v[j]);
  store8(dst + (size_t)i * 8, o);
}

// ---------------------------------------------------------------- GEMM ------
// C[m][n] = sum_e A[m][e] * B[n][e]   (both row-major along e, bf16)
// EPI 0: f32 store C[m*N+n].   EPI 1: bf16 store to Vt layout (m=dmodel, n=token).
template <int EPI>
__global__ __launch_bounds__(256) void gemm_nt(
    const ushort_t* __restrict__ A, const ushort_t* __restrict__ B,
    float* __restrict__ Cf, ushort_t* __restrict__ Cb, int M, int N, int K)
{
  __shared__ __align__(16) ushort_t As[128 * 64];
  __shared__ __align__(16) ushort_t Bs[128 * 64];
  const int l = threadIdx.x & 63;
  const int w = threadIdx.x >> 6;
  const int wm = w >> 1, wn = w & 1;
  const int mt = blockIdx.x % (M >> 7);
  const int nt = blockIdx.x / (M >> 7);
  const int m0 = mt << 7, n0 = nt << 7;

  const f32x4 zero4 = {0.f, 0.f, 0.f, 0.f};
  f32x4 acc[4][4];
#pragma unroll
  for (int i = 0; i < 4; ++i)
#pragma unroll
    for (int j = 0; j < 4; ++j) acc[i][j] = zero4;

  for (int k0 = 0; k0 < K; k0 += 64) {
#pragma unroll
    for (int i = 0; i < 4; ++i) {
      int ci = (w * 4 + i) * 64 + l;
      int r = ci >> 3, c = (ci & 7) ^ (r & 7);           // pre-swizzled source
      gl_lds16(A + (size_t)(m0 + r) * K + k0 + c * 8, &As[(w * 4 + i) * 512]);
      gl_lds16(B + (size_t)(n0 + r) * K + k0 + c * 8, &Bs[(w * 4 + i) * 512]);
    }
    __syncthreads();
#pragma unroll
    for (int kk = 0; kk < 2; ++kk) {
      bf16x8 af[4], bfr[4];
#pragma unroll
      for (int mi = 0; mi < 4; ++mi) {
        int r = wm * 64 + mi * 16 + (l & 15);
        int ch = ((l >> 4) + 4 * kk) ^ (r & 7);
        af[mi] = *(const bf16x8*)&As[r * 64 + ch * 8];
      }
#pragma unroll
      for (int ni = 0; ni < 4; ++ni) {
        int r = wn * 64 + ni * 16 + (l & 15);
        int ch = ((l >> 4) + 4 * kk) ^ (r & 7);
        bfr[ni] = *(const bf16x8*)&Bs[r * 64 + ch * 8];
      }
#pragma unroll
      for (int mi = 0; mi < 4; ++mi)
#pragma unroll
        for (int ni = 0; ni < 4; ++ni)
          acc[mi][ni] = __builtin_amdgcn_mfma_f32_16x16x32_bf16(af[mi], bfr[ni], acc[mi][ni], 0, 0, 0);
    }
    __syncthreads();
  }

#pragma unroll
  for (int mi = 0; mi < 4; ++mi)
#pragma unroll
    for (int ni = 0; ni < 4; ++ni)
#pragma unroll
      for (int reg = 0; reg < 4; ++reg) {
        int row = m0 + wm * 64 + mi * 16 + (l >> 4) * 4 + reg;
        int col = n0 + wn * 64 + ni * 16 + (l & 15);
        float v = acc[mi][ni][reg];
        if (EPI == 0) {
          Cf[(size_t)row * N + col] = v;
        } else {
          size_t o = (size_t)(col >> 11) * (1024 * 2048) + (size_t)row * 2048 + (col & 2047);
          Cb[o] = f2bf(v);
        }
      }
}

// ------------------------------------------------------------- attention ----
// Per block: one (b,h) and a 128-row q-block. 4 waves x 32 q-rows each.
// Swapped QK^T (mfma(K,Q)) keeps P lane-local: softmax entirely in registers,
// fixed offset exp(s-12), denominator reduced once after the k-loop.
// Q[b,h,s,128] (1/SCALE folded), K[b,h,s,128], Vt[b,h,d=64,s], out Ob[b,s,h*64+d].

template<bool MASKED>
__device__ __forceinline__ void attn_tile(
    const ushort_t* __restrict__ Kc, const ushort_t* __restrict__ Vc,
    const bf16x8 qf[2][4], f32x4 accO[2][4], float lsum[2],
    int kb, int qw, int lo, int g)
{
  const f32x4 zero4 = {0.f, 0.f, 0.f, 0.f};
  f32x4 sc[2][4];
#pragma unroll
  for (int qm = 0; qm < 2; ++qm)
#pragma unroll
    for (int ns = 0; ns < 4; ++ns) sc[qm][ns] = zero4;

  // S^T tile: sc[qm][ns], lane holds P[q=qw+qm*16+lo][k=kb+ns*16+g*4+reg]
#pragma unroll
  for (int e = 0; e < 4; ++e) {
#pragma unroll
    for (int ns = 0; ns < 4; ++ns) {
      int kr = ns * 16 + lo;
      int cc = (g + 4 * e) ^ (kr & 7);
      bf16x8 kf = *(const bf16x8*)&Kc[kr * 128 + cc * 8];
#pragma unroll
      for (int qm = 0; qm < 2; ++qm)
        sc[qm][ns] = __builtin_amdgcn_mfma_f32_16x16x32_bf16(kf, qf[qm][e], sc[qm][ns], 0, 0, 0);
    }
  }

  // exp + pack to PV A-fragments (registers only)
  bf16x8 pa[2][2];
#pragma unroll
  for (int qm = 0; qm < 2; ++qm) {
#pragma unroll
    for (int ns = 0; ns < 4; ++ns) {
#pragma unroll
      for (int reg = 0; reg < 4; ++reg) {
        float sv = sc[qm][ns][reg];
        if (MASKED) {
          int ka = kb + ns * 16 + g * 4 + reg;
          int qa = qw + qm * 16 + lo;
          sv = (ka <= qa) ? sv : -__builtin_inff();
        }
        float p = __expf(sv - SOFF);
        lsum[qm] += p;
        pa[qm][ns >> 1][(ns & 1) * 4 + reg] = (__bf16)p;
      }
    }
  }

  // O += P V : B-frag k-permutation matches P's lane-local k set
#pragma unroll
  for (int kk = 0; kk < 2; ++kk) {
#pragma unroll
    for (int nd = 0; nd < 4; ++nd) {
      int vr = nd * 16 + lo;
      int h8 = (g & 1) * 4;
      int cc0 = (4 * kk + (g >> 1)) ^ (vr & 7);
      int cc1 = (4 * kk + 2 + (g >> 1)) ^ (vr & 7);
      bf16x4 v0 = *(const bf16x4*)&Vc[vr * 64 + cc0 * 8 + h8];
      bf16x4 v1 = *(const bf16x4*)&Vc[vr * 64 + cc1 * 8 + h8];
      union { bf16x8 v8; bf16x4 v4[2]; } u;
      u.v4[0] = v0; u.v4[1] = v1;
#pragma unroll
      for (int qm = 0; qm < 2; ++qm)
        accO[qm][nd] = __builtin_amdgcn_mfma_f32_16x16x32_bf16(pa[qm][kk], u.v8, accO[qm][nd], 0, 0, 0);
    }
  }
}

__global__ __launch_bounds__(256) void attn_kernel(
    const ushort_t* __restrict__ Qs, const ushort_t* __restrict__ Ks,
    const ushort_t* __restrict__ Vt, ushort_t* __restrict__ Ob)
{
  const int S = 2048;
  const int qt = 15 - (blockIdx.x >> 5);    // heavy q-tiles first
  const int bh = blockIdx.x & 31;
  const int l = threadIdx.x & 63;
  const int w = threadIdx.x >> 6;
  const int g = l >> 4, lo = l & 15;

  __shared__ __align__(16) ushort_t Kl[2][64 * 128];  // 2 x 16KB
  __shared__ __align__(16) ushort_t Vl[2][64 * 64];   // 2 x 8KB

  const int q0b = qt * 128;
  const int qw = q0b + w * 32;
  const ushort_t* Kbase = Ks + (size_t)bh * S * 128;
  const ushort_t* Vbase = Vt + (size_t)bh * 64 * S;

  // Q fragments in registers: qf[qm][e] = Q[qw+qm*16+lo][32e+8g .. +7]
  bf16x8 qf[2][4];
#pragma unroll
  for (int qm = 0; qm < 2; ++qm) {
    const ushort_t* qp = Qs + ((size_t)bh * S + qw + qm * 16 + lo) * 128 + 8 * g;
#pragma unroll
    for (int e = 0; e < 4; ++e) qf[qm][e] = *(const bf16x8*)(qp + 32 * e);
  }

  const f32x4 zero4 = {0.f, 0.f, 0.f, 0.f};
  f32x4 accO[2][4];
  float lsum[2] = {0.f, 0.f};
#pragma unroll
  for (int qm = 0; qm < 2; ++qm)
#pragma unroll
    for (int nd = 0; nd < 4; ++nd) accO[qm][nd] = zero4;

  const int nt = 2 * qt + 2;

  // ---- staging helper (pre-swizzled source, linear LDS dest) ----
#define ATTN_STAGE(buf, kb_)                                                    \
  {                                                                             \
    int kb__ = (kb_);                                                           \
    _Pragma("unroll")                                                           \
    for (int i = 0; i < 4; ++i) {                                               \
      int ci = (w * 4 + i) * 64 + l;                                            \
      int r = ci >> 4, c = (ci & 15) ^ (r & 7);                                 \
      gl_lds16(Kbase + (size_t)(kb__ + r) * 128 + c * 8, &Kl[buf][(w * 4 + i) * 512]); \
    }                                                                           \
    _Pragma("unroll")                                                           \
    for (int i = 0; i < 2; ++i) {                                               \
      int ci = (w * 2 + i) * 64 + l;                                            \
      int r = ci >> 3, c = (ci & 7) ^ (r & 7);                                  \
      gl_lds16(Vbase + (size_t)r * S + kb__ + c * 8, &Vl[buf][(w * 2 + i) * 512]); \
    }                                                                           \
  }

  ATTN_STAGE(0, 0);
  __syncthreads();

  for (int t = 0; t < nt; ++t) {
    int cb = t & 1;
    if (t + 1 < nt) ATTN_STAGE(cb ^ 1, (t + 1) * 64);
    if (t < 2 * qt)
      attn_tile<false>(Kl[cb], Vl[cb], qf, accO, lsum, t * 64, qw, lo, g);
    else
      attn_tile<true>(Kl[cb], Vl[cb], qf, accO, lsum, t * 64, qw, lo, g);
    __syncthreads();
  }
#undef ATTN_STAGE

  // denominator: reduce across the 4 lane-groups, then redistribute to accO layout
#pragma unroll
  for (int qm = 0; qm < 2; ++qm) {
    lsum[qm] += __shfl_xor(lsum[qm], 16);
    lsum[qm] += __shfl_xor(lsum[qm], 32);
  }
  float linv[2][4];
#pragma unroll
  for (int qm = 0; qm < 2; ++qm)
#pragma unroll
    for (int reg = 0; reg < 4; ++reg)
      linv[qm][reg] = 1.0f / __shfl(lsum[qm], g * 4 + reg);

  const int b = bh >> 4, h = bh & 15;
#pragma unroll
  for (int qm = 0; qm < 2; ++qm)
#pragma unroll
    for (int nd = 0; nd < 4; ++nd)
#pragma unroll
      for (int reg = 0; reg < 4; ++reg) {
        int q = qw + qm * 16 + g * 4 + reg;
        int d = nd * 16 + lo;
        Ob[((size_t)(b * 2048 + q)) * 1024 + h * 64 + d] = f2bf(accO[qm][nd][reg] * linv[qm][reg]);
      }
}

// ---------------------------------------------------------------- launch ----
extern "C" void kernel_launch(void* const* d_in, const int* in_sizes, int n_in,
                              void* d_out, int out_size, void* d_ws, size_t ws_size,
                              hipStream_t stream) {
  const float* x  = (const float*)d_in[0];
  const float* wq = (const float*)d_in[1];
  const float* bq = (const float*)d_in[2];
  const float* wk = (const float*)d_in[3];
  const float* bk = (const float*)d_in[4];
  const float* vw = (const float*)d_in[5];
  const float* ow = (const float*)d_in[6];
  float* out = (float*)d_out;

  char* ws = (char*)d_ws;
  ushort_t* Qs  = (ushort_t*)(ws);                      // 16 MB  [32][2048][128]
  ushort_t* Ksb = (ushort_t*)(ws + (16u << 20));        // 16 MB  [32][2048][128]
  ushort_t* Vtb = (ushort_t*)(ws + (32u << 20));        //  8 MB  [32][64][2048]
  ushort_t* xbb = (ushort_t*)(ws + (40u << 20));        //  8 MB  [4096][1024]
  ushort_t* Obb = (ushort_t*)(ws + (48u << 20));        //  8 MB  [4096][1024]
  ushort_t* vwb = (ushort_t*)(ws + (56u << 20));        //  2 MB
  ushort_t* owb = (ushort_t*)(ws + (58u << 20));        //  2 MB

  prep_kernel<<<512, 256, 0, stream>>>(x, wq, bq, wk, bk, Qs, Ksb, xbb);
  wconv_kernel<<<1024, 256, 0, stream>>>(vw, ow, vwb, owb);
  // Vt[dm][token]: M=1024 rows of v_w, N=4096 tokens
  gemm_nt<1><<<256, 256, 0, stream>>>(vwb, xbb, nullptr, Vtb, 1024, 4096, 1024);
  attn_kernel<<<512, 256, 0, stream>>>(Qs, Ksb, Vtb, Obb);
  // out[token][dm] f32: M=4096 tokens, N=1024
  gemm_nt<0><<<256, 256, 0, stream>>>(Obb, owb, out, nullptr, 4096, 1024, 1024);
}